// Round 1
// baseline (80196.649 us; speedup 1.0000x reference)
//
#include <hip/hip_runtime.h>
#include <math.h>

// Problem constants
#define BSZ   64
#define TENC  512
#define CTXD  512
#define QD    1024
#define DD    512
#define PD    256
#define MR    160
#define SSTEP 500

#define ALIGN0 5120000ULL   // offset of alignments region in d_out (64*80*1000)

__device__ __forceinline__ float sigmoidf_(float x) { return 1.f / (1.f + expf(-x)); }

// ---------------------------------------------------------------------------
// Generic tiled transpose: dst[(dstRowOff + c)*dstLD + r] = src[r*C + c]
// ---------------------------------------------------------------------------
__global__ void k_transpose(const float* __restrict__ src, float* __restrict__ dst,
                            int R, int C, int dstLD, int dstRowOff) {
    __shared__ float tile[32][33];
    int c0 = blockIdx.x * 32, r0 = blockIdx.y * 32;
    int x = threadIdx.x;  // 0..31
    for (int y = threadIdx.y; y < 32; y += 8) {
        int r = r0 + y, c = c0 + x;
        if (r < R && c < C) tile[y][x] = src[(size_t)r * C + c];
    }
    __syncthreads();
    for (int y = threadIdx.y; y < 32; y += 8) {
        int c = c0 + y, r = r0 + x;
        if (r < R && c < C) dst[(size_t)(dstRowOff + c) * dstLD + r] = tile[x][y];
    }
}

__global__ void k_zero(float* p, int n) {
    int i = blockIdx.x * 256 + threadIdx.x;
    if (i < n) p[i] = 0.f;
}

// ---------------------------------------------------------------------------
// Prenet: pre[s][b][j] = relu( relu(x_s,b @ w1T)*bn @ w2T )*bn
// x_s,b = (s==0) ? mem_init : memory[b, (s-1)*160 .. +160)
// grid: 500 blocks (s), 256 threads (j)
// ---------------------------------------------------------------------------
__global__ __launch_bounds__(256) void k_prenet(
    const float* __restrict__ memory, const float* __restrict__ mem_init,
    const float* __restrict__ w1T, const float* __restrict__ w2T,
    float* __restrict__ pre) {
    const float BN = 0.99999500003749969f;  // 1/sqrt(1+1e-5)
    int s = blockIdx.x, j = threadIdx.x;
    __shared__ float h1[BSZ][PD];  // 64KB
    float acc[BSZ];
#pragma unroll
    for (int b = 0; b < BSZ; ++b) acc[b] = 0.f;
    if (s == 0) {
        for (int k = 0; k < MR; ++k) {
            float w = w1T[k * PD + j];
            float a = mem_init[k];
#pragma unroll
            for (int b = 0; b < BSZ; ++b) acc[b] = fmaf(a, w, acc[b]);
        }
    } else {
        const float* mb = memory + (size_t)(s - 1) * MR;
        for (int k = 0; k < MR; ++k) {
            float w = w1T[k * PD + j];
#pragma unroll
            for (int b = 0; b < BSZ; ++b)
                acc[b] = fmaf(mb[(size_t)b * 80000 + k], w, acc[b]);
        }
    }
#pragma unroll
    for (int b = 0; b < BSZ; ++b) h1[b][j] = fmaxf(acc[b], 0.f) * BN;
    __syncthreads();
#pragma unroll
    for (int b = 0; b < BSZ; ++b) acc[b] = 0.f;
    for (int k = 0; k < PD; ++k) {
        float w = w2T[k * PD + j];
#pragma unroll
        for (int b = 0; b < BSZ; ++b) acc[b] = fmaf(h1[b][k], w, acc[b]);
    }
    float* prow = pre + (size_t)s * BSZ * PD;
#pragma unroll
    for (int b = 0; b < BSZ; ++b) prow[b * PD + j] = fmaxf(acc[b], 0.f) * BN;
}

// ---------------------------------------------------------------------------
// Gate GEMMs: thread = output column n; lanes coalesce on transposed W.
// The 64 per-b activation loads are wave-uniform (scalar-pipe candidates).
// ---------------------------------------------------------------------------
template <int LD>
__device__ __forceinline__ void gemm_panel(const float* __restrict__ A,
                                           const float* __restrict__ Wcol,
                                           int NW, float acc[BSZ]) {
#pragma unroll 4
    for (int kk = 0; kk < 128; ++kk) {
        float w = Wcol[(size_t)kk * NW];
        const float* ar = A + kk;
#pragma unroll
        for (int b = 0; b < BSZ; ++b)
            acc[b] = fmaf(ar[(size_t)b * LD], w, acc[b]);
    }
}

// grid: 352 blocks. [0,224): att GEMM step t (t<500). [224,352): dec GEMM step t-1 (t>=1).
// att: K=1792 = pre(256) | ctx(512) | q(1024), chunks of 128, KS_A=14, 16 col-tiles of 256.
// dec: K=2048 = q(1024) | ctx(512) | dh(512), chunks of 128, KS_D=16, 8 col-tiles of 256.
__global__ __launch_bounds__(256) void k_gates(
    int t,
    const float* __restrict__ pre, const float* __restrict__ ctx_all,
    const float* __restrict__ ctx_init, const float* __restrict__ qbuf,
    const float* __restrict__ q_init, const float* __restrict__ dh_all,
    const float* __restrict__ dh_init, const float* __restrict__ WT_att,
    const float* __restrict__ WT_dec, float* __restrict__ gbufA,
    float* __restrict__ gbufD) {
    float acc[BSZ];
#pragma unroll
    for (int b = 0; b < BSZ; ++b) acc[b] = 0.f;
    int bid = blockIdx.x;
    if (bid < 224) {
        if (t >= SSTEP) return;
        int tile = bid / 14, ks = bid % 14;
        int n = tile * 256 + threadIdx.x;
        int k0 = ks * 128;
        const float* Wcol = WT_att + (size_t)k0 * 4096 + n;
        if (k0 < 256) {
            gemm_panel<PD>(pre + (size_t)t * BSZ * PD + k0, Wcol, 4096, acc);
        } else if (k0 < 768) {
            if (t == 0) gemm_panel<0>(ctx_init + (k0 - 256), Wcol, 4096, acc);
            else gemm_panel<CTXD>(ctx_all + (size_t)(t - 1) * BSZ * CTXD + (k0 - 256), Wcol, 4096, acc);
        } else {
            if (t == 0) gemm_panel<0>(q_init + (k0 - 768), Wcol, 4096, acc);
            else gemm_panel<QD>(qbuf + (size_t)((t - 1) & 1) * BSZ * QD + (k0 - 768), Wcol, 4096, acc);
        }
        float* g = gbufA + (size_t)ks * BSZ * 4096 + n;
#pragma unroll
        for (int b = 0; b < BSZ; ++b) g[(size_t)b * 4096] = acc[b];
    } else {
        if (t < 1) return;
        int r = bid - 224;
        int tile = r / 16, ks = r % 16;
        int n = tile * 256 + threadIdx.x;
        int k0 = ks * 128;
        int tm1 = t - 1;
        const float* Wcol = WT_dec + (size_t)k0 * 2048 + n;
        if (k0 < 1024) {
            gemm_panel<QD>(qbuf + (size_t)(tm1 & 1) * BSZ * QD + k0, Wcol, 2048, acc);
        } else if (k0 < 1536) {
            gemm_panel<CTXD>(ctx_all + (size_t)tm1 * BSZ * CTXD + (k0 - 1024), Wcol, 2048, acc);
        } else {
            if (t == 1) gemm_panel<0>(dh_init + (k0 - 1536), Wcol, 2048, acc);
            else gemm_panel<DD>(dh_all + (size_t)(t - 2) * BSZ * DD + (k0 - 1536), Wcol, 2048, acc);
        }
        float* g = gbufD + (size_t)ks * BSZ * 2048 + n;
#pragma unroll
        for (int b = 0; b < BSZ; ++b) g[(size_t)b * 2048] = acc[b];
    }
}

// ---------------------------------------------------------------------------
// State kernel: ta_{t-1} -> att pointwise (q_t) -> dec pointwise (dh_{t-1})
//               -> alpha_t (+ write alignments) -> ctx_t chunk
// grid: 256 blocks = (b, c) with c = d/j chunk; 256 threads.
// ---------------------------------------------------------------------------
__global__ __launch_bounds__(256) void k_state(
    int t,
    const float* __restrict__ inputs, const float* __restrict__ gbufA,
    const float* __restrict__ gbufD, const float* __restrict__ att_bih,
    const float* __restrict__ att_bhh, const float* __restrict__ dec_bih,
    const float* __restrict__ dec_bhh, const float* __restrict__ ta_u_w,
    const float* __restrict__ ta_u_b, const float* __restrict__ ta_sq_w,
    const float* __restrict__ ta_sq_b, float* ctx_all, float* qbuf,
    float* qc, float* dcbuf, float* dh_all, float* d_out) {
    int bid = blockIdx.x;
    int b = bid >> 2, c = bid & 3;
    int tid = threadIdx.x;
    __shared__ float red[256];
    __shared__ float alpha_s[TENC];
    __shared__ float anew[TENC];

    float u = 0.5f, sq = 1.4f;
    // ---- P0: ta for step t-1 (u,sq carried into alpha_t) ----
    if (t >= 1 && t < SSTEP) {
        const float* ctxp = ctx_all + ((size_t)(t - 1) * BSZ + b) * CTXD;
        const float* qp = qbuf + ((size_t)((t - 1) & 1) * BSZ + b) * QD;
        float du = 0.f, ds = 0.f;
        for (int e = tid; e < CTXD + QD; e += 256) {
            float x = (e < CTXD) ? ctxp[e] : qp[e - CTXD];
            du = fmaf(ta_u_w[e], x, du);
            ds = fmaf(ta_sq_w[e], x, ds);
        }
        red[tid] = du; __syncthreads();
        for (int s2 = 128; s2 > 0; s2 >>= 1) {
            if (tid < s2) red[tid] += red[tid + s2];
            __syncthreads();
        }
        float du_t = red[0]; __syncthreads();
        red[tid] = ds; __syncthreads();
        for (int s2 = 128; s2 > 0; s2 >>= 1) {
            if (tid < s2) red[tid] += red[tid + s2];
            __syncthreads();
        }
        float ds_t = red[0]; __syncthreads();
        u = sigmoidf_(du_t + ta_u_b[0]);
        sq = sigmoidf_(ds_t + ta_sq_b[0]) + 1.f;
    }

    // ---- P1: att-LSTM pointwise, produce q_t ----
    if (t < SSTEP) {
        int j = c * 256 + tid;
        float g4[4];
#pragma unroll
        for (int g = 0; g < 4; ++g) {
            int n = g * QD + j;
            float s = att_bih[n] + att_bhh[n];
            for (int ks = 0; ks < 14; ++ks) s += gbufA[((size_t)ks * BSZ + b) * 4096 + n];
            g4[g] = s;
        }
        float ig = sigmoidf_(g4[0]), fg = sigmoidf_(g4[1]);
        float gg = tanhf(g4[2]), og = sigmoidf_(g4[3]);
        size_t qi = (size_t)b * QD + j;
        float c2 = fg * qc[qi] + ig * gg;
        qc[qi] = c2;
        qbuf[(size_t)(t & 1) * BSZ * QD + qi] = og * tanhf(c2);
    }

    // ---- P2: dec-LSTM pointwise for step t-1, produce dh_{t-1} ----
    if (t >= 1 && tid < 128) {
        int j = c * 128 + tid;
        float g4[4];
#pragma unroll
        for (int g = 0; g < 4; ++g) {
            int n = g * DD + j;
            float s = dec_bih[n] + dec_bhh[n];
            for (int ks = 0; ks < 16; ++ks) s += gbufD[((size_t)ks * BSZ + b) * 2048 + n];
            g4[g] = s;
        }
        float ig = sigmoidf_(g4[0]), fg = sigmoidf_(g4[1]);
        float gg = tanhf(g4[2]), og = sigmoidf_(g4[3]);
        size_t di = (size_t)b * DD + j;
        float c2 = fg * dcbuf[di] + ig * gg;
        dcbuf[di] = c2;
        dh_all[((size_t)(t - 1) * BSZ + b) * DD + j] = og * tanhf(c2);
    }

    // ---- P3+P4: alpha recursion, normalize, alignments, ctx chunk ----
    if (t < SSTEP) {
        const float* aprev = d_out + ALIGN0 + ((size_t)b * SSTEP + (t - 1)) * TENC;
        for (int e = tid; e < TENC; e += 256)
            alpha_s[e] = (t == 0) ? (e == 0 ? 1.f : 1e-7f) : aprev[e];
        __syncthreads();
        float psum = 0.f;
        for (int e = tid; e < TENC; e += 256) {
            float av = alpha_s[e];
            float sh = (e == 0) ? 0.f : alpha_s[e - 1];
            float a = fmaf(1.f - u, av, u * sh) + 1e-6f;
            a = powf(a, sq);
            anew[e] = a;
            psum += a;
        }
        red[tid] = psum; __syncthreads();
        for (int s2 = 128; s2 > 0; s2 >>= 1) {
            if (tid < s2) red[tid] += red[tid + s2];
            __syncthreads();
        }
        float inv = 1.f / red[0];
        float* aout = d_out + ALIGN0 + ((size_t)b * SSTEP + t) * TENC;
        for (int e = tid; e < TENC; e += 256) {
            float an = anew[e] * inv;
            alpha_s[e] = an;
            if (c == 0) aout[e] = an;
        }
        __syncthreads();
        // ctx chunk: d = c*128 + (tid&127), halves over e
        int d = c * 128 + (tid & 127);
        int half = tid >> 7;
        const float* inp = inputs + (size_t)b * TENC * CTXD + d;
        float ps = 0.f;
        int e0 = half * 256;
#pragma unroll 8
        for (int e = e0; e < e0 + 256; ++e)
            ps = fmaf(alpha_s[e], inp[(size_t)e * CTXD], ps);
        red[tid] = ps; __syncthreads();
        if (tid < 128) {
            float v = red[tid] + red[tid + 128];
            ctx_all[((size_t)t * BSZ + b) * CTXD + c * 128 + tid] = v;
        }
    }
}

// ---------------------------------------------------------------------------
// Deferred projection: tmp_out[t][b][j] = [dh_t, ctx_t] @ proj_w.T + proj_b
// grid: 1000 blocks = (t, b-half); threads 256 (160 active)
// ---------------------------------------------------------------------------
__global__ __launch_bounds__(256) void k_proj(
    const float* __restrict__ dh_all, const float* __restrict__ ctx_all,
    const float* __restrict__ projT, const float* __restrict__ proj_b,
    float* __restrict__ tmp_out) {
    int t = blockIdx.x >> 1, bh = blockIdx.x & 1;
    int j = threadIdx.x;
    if (j >= MR) return;
    float acc[32];
#pragma unroll
    for (int i = 0; i < 32; ++i) acc[i] = 0.f;
    int b0 = bh * 32;
    const float* dhp = dh_all + ((size_t)t * BSZ + b0) * DD;
    const float* cxp = ctx_all + ((size_t)t * BSZ + b0) * CTXD;
    for (int k = 0; k < DD; ++k) {
        float w = projT[(size_t)k * MR + j];
#pragma unroll
        for (int i = 0; i < 32; ++i) acc[i] = fmaf(dhp[(size_t)i * DD + k], w, acc[i]);
    }
    for (int k = 0; k < CTXD; ++k) {
        float w = projT[(size_t)(DD + k) * MR + j];
#pragma unroll
        for (int i = 0; i < 32; ++i) acc[i] = fmaf(cxp[(size_t)i * CTXD + k], w, acc[i]);
    }
    float bias = proj_b[j];
    float* o = tmp_out + ((size_t)t * BSZ + b0) * MR + j;
#pragma unroll
    for (int i = 0; i < 32; ++i) o[(size_t)i * MR] = acc[i] + bias;
}

// ---------------------------------------------------------------------------
// Output transpose: d_out[b][m][2t+r] = tmp_out[t][b][r*80+m]
// grid: 640 blocks = (b, t-tile of 50); threads 256
// ---------------------------------------------------------------------------
__global__ __launch_bounds__(256) void k_otrans(const float* __restrict__ tmp_out,
                                                float* __restrict__ d_out) {
    int bid = blockIdx.x;
    int b = bid / 10, tt = bid % 10;
    int t0 = tt * 50;
    __shared__ float tile[50 * MR];
    for (int i = threadIdx.x; i < 50 * MR; i += 256) {
        int trow = i / MR, j = i % MR;
        tile[i] = tmp_out[((size_t)(t0 + trow) * BSZ + b) * MR + j];
    }
    __syncthreads();
    for (int i = threadIdx.x; i < 80 * 100; i += 256) {
        int m = i / 100, ff = i % 100;
        int trow = ff >> 1, r = ff & 1;
        d_out[(size_t)b * 80000 + (size_t)m * 1000 + 2 * t0 + ff] =
            tile[trow * MR + r * 80 + m];
    }
}

// ---------------------------------------------------------------------------
extern "C" void kernel_launch(void* const* d_in, const int* in_sizes, int n_in,
                              void* d_out_v, int out_size, void* d_ws, size_t ws_size,
                              hipStream_t stream) {
    const float* inputs   = (const float*)d_in[0];
    const float* memory   = (const float*)d_in[1];
    const float* w1       = (const float*)d_in[3];
    const float* w2       = (const float*)d_in[4];
    const float* att_wih  = (const float*)d_in[5];
    const float* att_whh  = (const float*)d_in[6];
    const float* att_bih  = (const float*)d_in[7];
    const float* att_bhh  = (const float*)d_in[8];
    const float* ta_u_w   = (const float*)d_in[9];
    const float* ta_u_b   = (const float*)d_in[10];
    const float* ta_sq_w  = (const float*)d_in[11];
    const float* ta_sq_b  = (const float*)d_in[12];
    const float* dec_wih  = (const float*)d_in[13];
    const float* dec_whh  = (const float*)d_in[14];
    const float* dec_bih  = (const float*)d_in[15];
    const float* dec_bhh  = (const float*)d_in[16];
    const float* proj_w   = (const float*)d_in[17];
    const float* proj_b   = (const float*)d_in[18];
    const float* q_init   = (const float*)d_in[19];
    const float* ctx_init = (const float*)d_in[20];
    const float* dh_init  = (const float*)d_in[21];
    const float* mem_init = (const float*)d_in[22];
    float* out = (float*)d_out_v;
    float* ws = (float*)d_ws;

    // ws arena (floats)
    size_t o = 0;
    float* WT_att  = ws + o; o += (size_t)1792 * 4096;   // 7,340,032
    float* WT_dec  = ws + o; o += (size_t)2048 * 2048;   // 4,194,304
    float* w1T     = ws + o; o += (size_t)160 * 256;
    float* w2T     = ws + o; o += (size_t)256 * 256;
    float* projT   = ws + o; o += (size_t)1024 * 160;
    float* pre     = ws + o; o += (size_t)SSTEP * BSZ * PD;    // 8,192,000
    float* gbufA   = ws + o; o += (size_t)14 * BSZ * 4096;     // 3,670,016
    float* gbufD   = ws + o; o += (size_t)16 * BSZ * 2048;     // 2,097,152
    float* qbuf    = ws + o; o += (size_t)2 * BSZ * QD;
    float* qc      = ws + o; o += (size_t)BSZ * QD;
    float* dc      = ws + o; o += (size_t)BSZ * DD;
    float* dh_all  = ws + o; o += (size_t)SSTEP * BSZ * DD;    // 16,384,000
    float* ctx_all = ws + o; o += (size_t)SSTEP * BSZ * CTXD;  // 16,384,000
    float* tmp_out = ws + o; o += (size_t)SSTEP * BSZ * MR;    // 5,120,000
    (void)ws_size; (void)in_sizes; (void)n_in; (void)out_size;

    dim3 tt(32, 8);
    // weight transposes
    k_transpose<<<dim3(24, 128), tt, 0, stream>>>(att_wih, WT_att, 4096, 768, 4096, 0);
    k_transpose<<<dim3(32, 128), tt, 0, stream>>>(att_whh, WT_att, 4096, 1024, 4096, 768);
    k_transpose<<<dim3(48, 64), tt, 0, stream>>>(dec_wih, WT_dec, 2048, 1536, 2048, 0);
    k_transpose<<<dim3(16, 64), tt, 0, stream>>>(dec_whh, WT_dec, 2048, 512, 2048, 1536);
    k_transpose<<<dim3(5, 8), tt, 0, stream>>>(w1, w1T, 256, 160, 256, 0);
    k_transpose<<<dim3(8, 8), tt, 0, stream>>>(w2, w2T, 256, 256, 256, 0);
    k_transpose<<<dim3(32, 5), tt, 0, stream>>>(proj_w, projT, 160, 1024, 160, 0);
    // zero LSTM cell states (qc, dc are contiguous in the arena)
    k_zero<<<dim3(384), dim3(256), 0, stream>>>(qc, BSZ * QD + BSZ * DD);
    // prenet for all steps
    k_prenet<<<dim3(SSTEP), dim3(256), 0, stream>>>(memory, mem_init, w1T, w2T, pre);

    // main recurrence: 2 kernels per step (t = 0..500; edge steps partially active)
    for (int t = 0; t <= SSTEP; ++t) {
        k_gates<<<dim3(352), dim3(256), 0, stream>>>(
            t, pre, ctx_all, ctx_init, qbuf, q_init, dh_all, dh_init,
            WT_att, WT_dec, gbufA, gbufD);
        k_state<<<dim3(256), dim3(256), 0, stream>>>(
            t, inputs, gbufA, gbufD, att_bih, att_bhh, dec_bih, dec_bhh,
            ta_u_w, ta_u_b, ta_sq_w, ta_sq_b, ctx_all, qbuf, qc, dc, dh_all, out);
    }

    // deferred projection + output layout transpose
    k_proj<<<dim3(1000), dim3(256), 0, stream>>>(dh_all, ctx_all, projT, proj_b, tmp_out);
    k_otrans<<<dim3(640), dim3(256), 0, stream>>>(tmp_out, out);
}

// Round 3
// 26280.869 us; speedup vs baseline: 3.0515x; 3.0515x over previous
//
#include <hip/hip_runtime.h>
#include <math.h>

// Problem constants
#define BSZ   64
#define TENC  512
#define CTXD  512
#define QD    1024
#define DD    512
#define PD    256
#define MR    160
#define SSTEP 500
#define KC    32    // LDS staging sub-chunk along K

#define ALIGN0 5120000ULL   // offset of alignments region in d_out (64*80*1000)

__device__ __forceinline__ float sigmoidf_(float x) { return 1.f / (1.f + expf(-x)); }

// ---------------------------------------------------------------------------
// Generic tiled transpose: dst[(dstRowOff + c)*dstLD + r] = src[r*C + c]
// ---------------------------------------------------------------------------
__global__ void k_transpose(const float* __restrict__ src, float* __restrict__ dst,
                            int R, int C, int dstLD, int dstRowOff) {
    __shared__ float tile[32][33];
    int c0 = blockIdx.x * 32, r0 = blockIdx.y * 32;
    int x = threadIdx.x;  // 0..31
    for (int y = threadIdx.y; y < 32; y += 8) {
        int r = r0 + y, c = c0 + x;
        if (r < R && c < C) tile[y][x] = src[(size_t)r * C + c];
    }
    __syncthreads();
    for (int y = threadIdx.y; y < 32; y += 8) {
        int c = c0 + y, r = r0 + x;
        if (r < R && c < C) dst[(size_t)(dstRowOff + c) * dstLD + r] = tile[x][y];
    }
}

__global__ void k_zero(float* p, int n) {
    int i = blockIdx.x * 256 + threadIdx.x;
    if (i < n) p[i] = 0.f;
}

// ---------------------------------------------------------------------------
// Prenet: pre[s][b][j] = relu( relu(x_s,b @ w1T)*bn @ w2T )*bn   (runs once)
// ---------------------------------------------------------------------------
__global__ __launch_bounds__(256) void k_prenet(
    const float* __restrict__ memory, const float* __restrict__ mem_init,
    const float* __restrict__ w1T, const float* __restrict__ w2T,
    float* __restrict__ pre) {
    const float BN = 0.99999500003749969f;  // 1/sqrt(1+1e-5)
    int s = blockIdx.x, j = threadIdx.x;
    __shared__ float h1[BSZ][PD];  // 64KB
    float acc[BSZ];
#pragma unroll
    for (int b = 0; b < BSZ; ++b) acc[b] = 0.f;
    if (s == 0) {
        for (int k = 0; k < MR; ++k) {
            float w = w1T[k * PD + j];
            float a = mem_init[k];
#pragma unroll
            for (int b = 0; b < BSZ; ++b) acc[b] = fmaf(a, w, acc[b]);
        }
    } else {
        const float* mb = memory + (size_t)(s - 1) * MR;
        for (int k = 0; k < MR; ++k) {
            float w = w1T[k * PD + j];
#pragma unroll
            for (int b = 0; b < BSZ; ++b)
                acc[b] = fmaf(mb[(size_t)b * 80000 + k], w, acc[b]);
        }
    }
#pragma unroll
    for (int b = 0; b < BSZ; ++b) h1[b][j] = fmaxf(acc[b], 0.f) * BN;
    __syncthreads();
#pragma unroll
    for (int b = 0; b < BSZ; ++b) acc[b] = 0.f;
    for (int k = 0; k < PD; ++k) {
        float w = w2T[k * PD + j];
#pragma unroll
        for (int b = 0; b < BSZ; ++b) acc[b] = fmaf(h1[b][k], w, acc[b]);
    }
    float* prow = pre + (size_t)s * BSZ * PD;
#pragma unroll
    for (int b = 0; b < BSZ; ++b) prow[b * PD + j] = fmaxf(acc[b], 0.f) * BN;
}

// ---------------------------------------------------------------------------
// Gate GEMMs, LDS-staged + register-tiled (8b x 4n per thread).
// grid 704: [0,448) att = 32 n-tiles(128) x 14 k-chunks(128)
//           [448,704) dec = 16 n-tiles(128) x 16 k-chunks(128)
// Each k-chunk lies in exactly one activation segment -> single (Asrc,lda).
// ---------------------------------------------------------------------------
__global__ __launch_bounds__(256) void k_gates(
    int t,
    const float* __restrict__ pre, const float* __restrict__ ctx_all,
    const float* __restrict__ ctx_init, const float* __restrict__ qbuf,
    const float* __restrict__ q_init, const float* __restrict__ dh_all,
    const float* __restrict__ dh_init, const float* __restrict__ WT_att,
    const float* __restrict__ WT_dec, float* __restrict__ gbufA,
    float* __restrict__ gbufD) {
    __shared__ __align__(16) float As[BSZ][KC + 4];   // +4 pad keeps 16B align, breaks bank stride
    __shared__ __align__(16) float Ws[KC][128];

    int bid = blockIdx.x;
    const float* Asrc; int lda; const float* Wsrc; float* gout; int NW;
    if (bid < 448) {
        if (t >= SSTEP) return;
        int tile = bid / 14, ks = bid % 14;
        int k0 = ks * 128;
        NW = 4096;
        Wsrc = WT_att + (size_t)k0 * 4096 + tile * 128;
        gout = gbufA + (size_t)ks * BSZ * 4096 + tile * 128;
        if (k0 < 256) { Asrc = pre + (size_t)t * BSZ * PD + k0; lda = PD; }
        else if (k0 < 768) {
            if (t == 0) { Asrc = ctx_init + (k0 - 256); lda = 0; }
            else { Asrc = ctx_all + (size_t)(t - 1) * BSZ * CTXD + (k0 - 256); lda = CTXD; }
        } else {
            if (t == 0) { Asrc = q_init + (k0 - 768); lda = 0; }
            else { Asrc = qbuf + (size_t)((t - 1) & 1) * BSZ * QD + (k0 - 768); lda = QD; }
        }
    } else {
        if (t < 1) return;
        int r = bid - 448;
        int tile = r / 16, ks = r % 16;
        int k0 = ks * 128;
        int tm1 = t - 1;
        NW = 2048;
        Wsrc = WT_dec + (size_t)k0 * 2048 + tile * 128;
        gout = gbufD + (size_t)ks * BSZ * 2048 + tile * 128;
        if (k0 < 1024) { Asrc = qbuf + (size_t)(tm1 & 1) * BSZ * QD + k0; lda = QD; }
        else if (k0 < 1536) { Asrc = ctx_all + (size_t)tm1 * BSZ * CTXD + (k0 - 1024); lda = CTXD; }
        else {
            if (t == 1) { Asrc = dh_init + (k0 - 1536); lda = 0; }
            else { Asrc = dh_all + (size_t)(t - 2) * BSZ * DD + (k0 - 1536); lda = DD; }
        }
    }

    int tid = threadIdx.x;
    int ng = tid & 31, bg = tid >> 5;   // n-group 0..31 (4n each), b-group 0..7 (8b each)
    float acc[8][4];
#pragma unroll
    for (int i = 0; i < 8; ++i)
#pragma unroll
        for (int j = 0; j < 4; ++j) acc[i][j] = 0.f;

    for (int c = 0; c < 4; ++c) {       // 4 sub-chunks of KC=32 covering this 128-K chunk
        __syncthreads();
        // stage A: 64b x 32k = 512 float4
#pragma unroll
        for (int r2 = 0; r2 < 2; ++r2) {
            int idx = tid + r2 * 256;
            int b = idx >> 3, kq = idx & 7;
            const float4 v = *(const float4*)(Asrc + (size_t)b * lda + c * KC + kq * 4);
            *(float4*)&As[b][kq * 4] = v;
        }
        // stage W: 32k x 128n = 1024 float4
#pragma unroll
        for (int r2 = 0; r2 < 4; ++r2) {
            int idx = tid + r2 * 256;
            int kk = idx >> 5, nq = idx & 31;
            const float4 v = *(const float4*)(Wsrc + (size_t)(c * KC + kk) * NW + nq * 4);
            *(float4*)&Ws[kk][nq * 4] = v;
        }
        __syncthreads();
#pragma unroll
        for (int kq = 0; kq < KC / 4; ++kq) {
            float4 w0 = *(float4*)&Ws[kq * 4 + 0][ng * 4];
            float4 w1 = *(float4*)&Ws[kq * 4 + 1][ng * 4];
            float4 w2 = *(float4*)&Ws[kq * 4 + 2][ng * 4];
            float4 w3 = *(float4*)&Ws[kq * 4 + 3][ng * 4];
#pragma unroll
            for (int i = 0; i < 8; ++i) {
                float4 a = *(float4*)&As[bg * 8 + i][kq * 4];
                acc[i][0] = fmaf(a.x, w0.x, acc[i][0]);
                acc[i][1] = fmaf(a.x, w0.y, acc[i][1]);
                acc[i][2] = fmaf(a.x, w0.z, acc[i][2]);
                acc[i][3] = fmaf(a.x, w0.w, acc[i][3]);
                acc[i][0] = fmaf(a.y, w1.x, acc[i][0]);
                acc[i][1] = fmaf(a.y, w1.y, acc[i][1]);
                acc[i][2] = fmaf(a.y, w1.z, acc[i][2]);
                acc[i][3] = fmaf(a.y, w1.w, acc[i][3]);
                acc[i][0] = fmaf(a.z, w2.x, acc[i][0]);
                acc[i][1] = fmaf(a.z, w2.y, acc[i][1]);
                acc[i][2] = fmaf(a.z, w2.z, acc[i][2]);
                acc[i][3] = fmaf(a.z, w2.w, acc[i][3]);
                acc[i][0] = fmaf(a.w, w3.x, acc[i][0]);
                acc[i][1] = fmaf(a.w, w3.y, acc[i][1]);
                acc[i][2] = fmaf(a.w, w3.z, acc[i][2]);
                acc[i][3] = fmaf(a.w, w3.w, acc[i][3]);
            }
        }
    }
    // write 8 x float4 partial results
#pragma unroll
    for (int i = 0; i < 8; ++i) {
        int b = bg * 8 + i;
        float4 v = make_float4(acc[i][0], acc[i][1], acc[i][2], acc[i][3]);
        *(float4*)(gout + (size_t)b * NW + ng * 4) = v;
    }
}

// ---------------------------------------------------------------------------
// State kernel: ta_{t-1} -> att pointwise (q_t) -> dec pointwise (dh_{t-1})
//               -> alpha_t (+ write alignments) -> ctx_t chunk
// grid: 256 blocks = (b, c) with c = d/j chunk; 256 threads.
// ---------------------------------------------------------------------------
__global__ __launch_bounds__(256) void k_state(
    int t,
    const float* __restrict__ inputs, const float* __restrict__ gbufA,
    const float* __restrict__ gbufD, const float* __restrict__ att_bih,
    const float* __restrict__ att_bhh, const float* __restrict__ dec_bih,
    const float* __restrict__ dec_bhh, const float* __restrict__ ta_u_w,
    const float* __restrict__ ta_u_b, const float* __restrict__ ta_sq_w,
    const float* __restrict__ ta_sq_b, float* ctx_all, float* qbuf,
    float* qc, float* dcbuf, float* dh_all, float* d_out) {
    int bid = blockIdx.x;
    int b = bid >> 2, c = bid & 3;
    int tid = threadIdx.x;
    __shared__ float red[256];
    __shared__ float alpha_s[TENC];
    __shared__ float anew[TENC];

    float u = 0.5f, sq = 1.4f;
    // ---- P0: ta for step t-1 (u,sq carried into alpha_t) ----
    if (t >= 1 && t < SSTEP) {
        const float* ctxp = ctx_all + ((size_t)(t - 1) * BSZ + b) * CTXD;
        const float* qp = qbuf + ((size_t)((t - 1) & 1) * BSZ + b) * QD;
        float du = 0.f, ds = 0.f;
        for (int e = tid; e < CTXD + QD; e += 256) {
            float x = (e < CTXD) ? ctxp[e] : qp[e - CTXD];
            du = fmaf(ta_u_w[e], x, du);
            ds = fmaf(ta_sq_w[e], x, ds);
        }
        red[tid] = du; __syncthreads();
        for (int s2 = 128; s2 > 0; s2 >>= 1) {
            if (tid < s2) red[tid] += red[tid + s2];
            __syncthreads();
        }
        float du_t = red[0]; __syncthreads();
        red[tid] = ds; __syncthreads();
        for (int s2 = 128; s2 > 0; s2 >>= 1) {
            if (tid < s2) red[tid] += red[tid + s2];
            __syncthreads();
        }
        float ds_t = red[0]; __syncthreads();
        u = sigmoidf_(du_t + ta_u_b[0]);
        sq = sigmoidf_(ds_t + ta_sq_b[0]) + 1.f;
    }

    // ---- P1: att-LSTM pointwise, produce q_t ----
    if (t < SSTEP) {
        int j = c * 256 + tid;
        float g4[4];
#pragma unroll
        for (int g = 0; g < 4; ++g) {
            int n = g * QD + j;
            float s = att_bih[n] + att_bhh[n];
            for (int ks = 0; ks < 14; ++ks) s += gbufA[((size_t)ks * BSZ + b) * 4096 + n];
            g4[g] = s;
        }
        float ig = sigmoidf_(g4[0]), fg = sigmoidf_(g4[1]);
        float gg = tanhf(g4[2]), og = sigmoidf_(g4[3]);
        size_t qi = (size_t)b * QD + j;
        float c2 = fg * qc[qi] + ig * gg;
        qc[qi] = c2;
        qbuf[(size_t)(t & 1) * BSZ * QD + qi] = og * tanhf(c2);
    }

    // ---- P2: dec-LSTM pointwise for step t-1, produce dh_{t-1} ----
    if (t >= 1 && tid < 128) {
        int j = c * 128 + tid;
        float g4[4];
#pragma unroll
        for (int g = 0; g < 4; ++g) {
            int n = g * DD + j;
            float s = dec_bih[n] + dec_bhh[n];
            for (int ks = 0; ks < 16; ++ks) s += gbufD[((size_t)ks * BSZ + b) * 2048 + n];
            g4[g] = s;
        }
        float ig = sigmoidf_(g4[0]), fg = sigmoidf_(g4[1]);
        float gg = tanhf(g4[2]), og = sigmoidf_(g4[3]);
        size_t di = (size_t)b * DD + j;
        float c2 = fg * dcbuf[di] + ig * gg;
        dcbuf[di] = c2;
        dh_all[((size_t)(t - 1) * BSZ + b) * DD + j] = og * tanhf(c2);
    }

    // ---- P3+P4: alpha recursion, normalize, alignments, ctx chunk ----
    if (t < SSTEP) {
        const float* aprev = d_out + ALIGN0 + ((size_t)b * SSTEP + (t - 1)) * TENC;
        for (int e = tid; e < TENC; e += 256)
            alpha_s[e] = (t == 0) ? (e == 0 ? 1.f : 1e-7f) : aprev[e];
        __syncthreads();
        float psum = 0.f;
        for (int e = tid; e < TENC; e += 256) {
            float av = alpha_s[e];
            float sh = (e == 0) ? 0.f : alpha_s[e - 1];
            float a = fmaf(1.f - u, av, u * sh) + 1e-6f;
            a = powf(a, sq);
            anew[e] = a;
            psum += a;
        }
        red[tid] = psum; __syncthreads();
        for (int s2 = 128; s2 > 0; s2 >>= 1) {
            if (tid < s2) red[tid] += red[tid + s2];
            __syncthreads();
        }
        float inv = 1.f / red[0];
        float* aout = d_out + ALIGN0 + ((size_t)b * SSTEP + t) * TENC;
        for (int e = tid; e < TENC; e += 256) {
            float an = anew[e] * inv;
            alpha_s[e] = an;
            if (c == 0) aout[e] = an;
        }
        __syncthreads();
        // ctx chunk: d = c*128 + (tid&127), halves over e
        int d = c * 128 + (tid & 127);
        int half = tid >> 7;
        const float* inp = inputs + (size_t)b * TENC * CTXD + d;
        float ps = 0.f;
        int e0 = half * 256;
#pragma unroll 8
        for (int e = e0; e < e0 + 256; ++e)
            ps = fmaf(alpha_s[e], inp[(size_t)e * CTXD], ps);
        red[tid] = ps; __syncthreads();
        if (tid < 128) {
            float v = red[tid] + red[tid + 128];
            ctx_all[((size_t)t * BSZ + b) * CTXD + c * 128 + tid] = v;
        }
    }
}

// ---------------------------------------------------------------------------
// Deferred projection: tmp_out[t][b][j] = [dh_t, ctx_t] @ proj_w.T + proj_b
// ---------------------------------------------------------------------------
__global__ __launch_bounds__(256) void k_proj(
    const float* __restrict__ dh_all, const float* __restrict__ ctx_all,
    const float* __restrict__ projT, const float* __restrict__ proj_b,
    float* __restrict__ tmp_out) {
    int t = blockIdx.x >> 1, bh = blockIdx.x & 1;
    int j = threadIdx.x;
    if (j >= MR) return;
    float acc[32];
#pragma unroll
    for (int i = 0; i < 32; ++i) acc[i] = 0.f;
    int b0 = bh * 32;
    const float* dhp = dh_all + ((size_t)t * BSZ + b0) * DD;
    const float* cxp = ctx_all + ((size_t)t * BSZ + b0) * CTXD;
    for (int k = 0; k < DD; ++k) {
        float w = projT[(size_t)k * MR + j];
#pragma unroll
        for (int i = 0; i < 32; ++i) acc[i] = fmaf(dhp[(size_t)i * DD + k], w, acc[i]);
    }
    for (int k = 0; k < CTXD; ++k) {
        float w = projT[(size_t)(DD + k) * MR + j];
#pragma unroll
        for (int i = 0; i < 32; ++i) acc[i] = fmaf(cxp[(size_t)i * CTXD + k], w, acc[i]);
    }
    float bias = proj_b[j];
    float* o = tmp_out + ((size_t)t * BSZ + b0) * MR + j;
#pragma unroll
    for (int i = 0; i < 32; ++i) o[(size_t)i * MR] = acc[i] + bias;
}

// ---------------------------------------------------------------------------
// Output transpose: d_out[b][m][2t+r] = tmp_out[t][b][r*80+m]
// ---------------------------------------------------------------------------
__global__ __launch_bounds__(256) void k_otrans(const float* __restrict__ tmp_out,
                                                float* __restrict__ d_out) {
    int bid = blockIdx.x;
    int b = bid / 10, tt = bid % 10;
    int t0 = tt * 50;
    __shared__ float tile[50 * MR];
    for (int i = threadIdx.x; i < 50 * MR; i += 256) {
        int trow = i / MR, j = i % MR;
        tile[i] = tmp_out[((size_t)(t0 + trow) * BSZ + b) * MR + j];
    }
    __syncthreads();
    for (int i = threadIdx.x; i < 80 * 100; i += 256) {
        int m = i / 100, ff = i % 100;
        int trow = ff >> 1, r = ff & 1;
        d_out[(size_t)b * 80000 + (size_t)m * 1000 + 2 * t0 + ff] =
            tile[trow * MR + r * 80 + m];
    }
}

// ---------------------------------------------------------------------------
extern "C" void kernel_launch(void* const* d_in, const int* in_sizes, int n_in,
                              void* d_out_v, int out_size, void* d_ws, size_t ws_size,
                              hipStream_t stream) {
    const float* inputs   = (const float*)d_in[0];
    const float* memory   = (const float*)d_in[1];
    const float* w1       = (const float*)d_in[3];
    const float* w2       = (const float*)d_in[4];
    const float* att_wih  = (const float*)d_in[5];
    const float* att_whh  = (const float*)d_in[6];
    const float* att_bih  = (const float*)d_in[7];
    const float* att_bhh  = (const float*)d_in[8];
    const float* ta_u_w   = (const float*)d_in[9];
    const float* ta_u_b   = (const float*)d_in[10];
    const float* ta_sq_w  = (const float*)d_in[11];
    const float* ta_sq_b  = (const float*)d_in[12];
    const float* dec_wih  = (const float*)d_in[13];
    const float* dec_whh  = (const float*)d_in[14];
    const float* dec_bih  = (const float*)d_in[15];
    const float* dec_bhh  = (const float*)d_in[16];
    const float* proj_w   = (const float*)d_in[17];
    const float* proj_b   = (const float*)d_in[18];
    const float* q_init   = (const float*)d_in[19];
    const float* ctx_init = (const float*)d_in[20];
    const float* dh_init  = (const float*)d_in[21];
    const float* mem_init = (const float*)d_in[22];
    float* out = (float*)d_out_v;
    float* ws = (float*)d_ws;

    // ws arena (floats)
    size_t o = 0;
    float* WT_att  = ws + o; o += (size_t)1792 * 4096;
    float* WT_dec  = ws + o; o += (size_t)2048 * 2048;
    float* w1T     = ws + o; o += (size_t)160 * 256;
    float* w2T     = ws + o; o += (size_t)256 * 256;
    float* projT   = ws + o; o += (size_t)1024 * 160;
    float* pre     = ws + o; o += (size_t)SSTEP * BSZ * PD;
    float* gbufA   = ws + o; o += (size_t)14 * BSZ * 4096;
    float* gbufD   = ws + o; o += (size_t)16 * BSZ * 2048;
    float* qbuf    = ws + o; o += (size_t)2 * BSZ * QD;
    float* qc      = ws + o; o += (size_t)BSZ * QD;
    float* dc      = ws + o; o += (size_t)BSZ * DD;
    float* dh_all  = ws + o; o += (size_t)SSTEP * BSZ * DD;
    float* ctx_all = ws + o; o += (size_t)SSTEP * BSZ * CTXD;
    float* tmp_out = ws + o; o += (size_t)SSTEP * BSZ * MR;
    (void)ws_size; (void)in_sizes; (void)n_in; (void)out_size;

    dim3 tt(32, 8);
    // weight transposes
    k_transpose<<<dim3(24, 128), tt, 0, stream>>>(att_wih, WT_att, 4096, 768, 4096, 0);
    k_transpose<<<dim3(32, 128), tt, 0, stream>>>(att_whh, WT_att, 4096, 1024, 4096, 768);
    k_transpose<<<dim3(48, 64), tt, 0, stream>>>(dec_wih, WT_dec, 2048, 1536, 2048, 0);
    k_transpose<<<dim3(16, 64), tt, 0, stream>>>(dec_whh, WT_dec, 2048, 512, 2048, 1536);
    k_transpose<<<dim3(5, 8), tt, 0, stream>>>(w1, w1T, 256, 160, 256, 0);
    k_transpose<<<dim3(8, 8), tt, 0, stream>>>(w2, w2T, 256, 256, 256, 0);
    k_transpose<<<dim3(32, 5), tt, 0, stream>>>(proj_w, projT, 160, 1024, 160, 0);
    // zero LSTM cell states (qc, dc contiguous in arena)
    k_zero<<<dim3(384), dim3(256), 0, stream>>>(qc, BSZ * QD + BSZ * DD);
    // prenet for all steps
    k_prenet<<<dim3(SSTEP), dim3(256), 0, stream>>>(memory, mem_init, w1T, w2T, pre);

    // main recurrence: 2 kernels per step
    for (int t = 0; t <= SSTEP; ++t) {
        k_gates<<<dim3(704), dim3(256), 0, stream>>>(
            t, pre, ctx_all, ctx_init, qbuf, q_init, dh_all, dh_init,
            WT_att, WT_dec, gbufA, gbufD);
        k_state<<<dim3(256), dim3(256), 0, stream>>>(
            t, inputs, gbufA, gbufD, att_bih, att_bhh, dec_bih, dec_bhh,
            ta_u_w, ta_u_b, ta_sq_w, ta_sq_b, ctx_all, qbuf, qc, dc, dh_all, out);
    }

    // deferred projection + output layout transpose
    k_proj<<<dim3(1000), dim3(256), 0, stream>>>(dh_all, ctx_all, projT, proj_b, tmp_out);
    k_otrans<<<dim3(640), dim3(256), 0, stream>>>(tmp_out, out);
}

// Round 8
// 21865.251 us; speedup vs baseline: 3.6678x; 1.2019x over previous
//
#include <hip/hip_runtime.h>
#include <math.h>

// Problem constants
#define BSZ   64
#define TENC  512
#define CTXD  512
#define QD    1024
#define DD    512
#define PD    256
#define MR    160
#define SSTEP 500
#define KATT  1792
#define KDEC  2048

#define ALIGN0 5120000ULL   // offset of alignments region in d_out (64*80*1000)

typedef __attribute__((ext_vector_type(8))) short bf16x8;
typedef __attribute__((ext_vector_type(4))) float f32x4;

__device__ __forceinline__ float sigmoidf_(float x) { return 1.f / (1.f + expf(-x)); }

// round-to-nearest-even fp32 -> bf16 hi/lo split
__device__ __forceinline__ void bfsplit(float x, unsigned short& h, unsigned short& l) {
    unsigned u = __float_as_uint(x);
    unsigned hb = (u + 0x7FFFu + ((u >> 16) & 1u)) >> 16;
    float hf = __uint_as_float(hb << 16);
    float r = x - hf;
    unsigned v = __float_as_uint(r);
    l = (unsigned short)((v + 0x7FFFu + ((v >> 16) & 1u)) >> 16);
    h = (unsigned short)hb;
}

// ---------------------------------------------------------------------------
// Small transposes (w1, w2, proj only)
// ---------------------------------------------------------------------------
__global__ void k_transpose(const float* __restrict__ src, float* __restrict__ dst,
                            int R, int C, int dstLD, int dstRowOff) {
    __shared__ float tile[32][33];
    int c0 = blockIdx.x * 32, r0 = blockIdx.y * 32;
    int x = threadIdx.x;
    for (int y = threadIdx.y; y < 32; y += 8) {
        int r = r0 + y, c = c0 + x;
        if (r < R && c < C) tile[y][x] = src[(size_t)r * C + c];
    }
    __syncthreads();
    for (int y = threadIdx.y; y < 32; y += 8) {
        int c = c0 + y, r = r0 + x;
        if (r < R && c < C) dst[(size_t)(dstRowOff + c) * dstLD + r] = tile[x][y];
    }
}

__global__ void k_zero(float* p, int n) {
    int i = blockIdx.x * 256 + threadIdx.x;
    if (i < n) p[i] = 0.f;
}

// ---------------------------------------------------------------------------
// One-time weight bf16 hi/lo splits, [n][k] layout (concat along k)
// ---------------------------------------------------------------------------
__global__ __launch_bounds__(256) void k_wsplit_att(
    const float* __restrict__ wih, const float* __restrict__ whh,
    unsigned short* __restrict__ WH, unsigned short* __restrict__ WL) {
    int idx = blockIdx.x * 256 + threadIdx.x;   // 4096*1792 = 7340032
    int n = idx / KATT, k = idx % KATT;
    float w = (k < 768) ? wih[(size_t)n * 768 + k] : whh[(size_t)n * 1024 + (k - 768)];
    unsigned short h, l; bfsplit(w, h, l);
    WH[idx] = h; WL[idx] = l;
}

__global__ __launch_bounds__(256) void k_wsplit_dec(
    const float* __restrict__ wih, const float* __restrict__ whh,
    unsigned short* __restrict__ WH, unsigned short* __restrict__ WL) {
    int idx = blockIdx.x * 256 + threadIdx.x;   // 2048*2048 = 4194304
    int n = idx / KDEC, k = idx % KDEC;
    float w = (k < 1536) ? wih[(size_t)n * 1536 + k] : whh[(size_t)n * 512 + (k - 1536)];
    unsigned short h, l; bfsplit(w, h, l);
    WH[idx] = h; WL[idx] = l;
}

// broadcast init vectors into [64][dim] bf16 hi/lo arrays
__global__ __launch_bounds__(256) void k_initsplit(
    const float* __restrict__ q_init, const float* __restrict__ ctx_init,
    const float* __restrict__ dh_init,
    unsigned short* qIH, unsigned short* qIL, unsigned short* cIH,
    unsigned short* cIL, unsigned short* dIH, unsigned short* dIL) {
    int idx = blockIdx.x * 256 + threadIdx.x;   // 64*2048 = 131072
    int b = idx >> 11, p = idx & 2047;
    unsigned short h, l;
    if (p < 1024) { bfsplit(q_init[p], h, l); qIH[b * 1024 + p] = h; qIL[b * 1024 + p] = l; }
    else if (p < 1536) { int j = p - 1024; bfsplit(ctx_init[j], h, l); cIH[b * 512 + j] = h; cIL[b * 512 + j] = l; }
    else { int j = p - 1536; bfsplit(dh_init[j], h, l); dIH[b * 512 + j] = h; dIL[b * 512 + j] = l; }
}

// ---------------------------------------------------------------------------
// Prenet (fp32 internally, writes bf16 hi/lo): pre[s][b][j]
// ---------------------------------------------------------------------------
__global__ __launch_bounds__(256) void k_prenet(
    const float* __restrict__ memory, const float* __restrict__ mem_init,
    const float* __restrict__ w1T, const float* __restrict__ w2T,
    unsigned short* __restrict__ preH, unsigned short* __restrict__ preL) {
    const float BN = 0.99999500003749969f;  // 1/sqrt(1+1e-5)
    int s = blockIdx.x, j = threadIdx.x;
    __shared__ float h1[BSZ][PD];
    float acc[BSZ];
#pragma unroll
    for (int b = 0; b < BSZ; ++b) acc[b] = 0.f;
    if (s == 0) {
        for (int k = 0; k < MR; ++k) {
            float w = w1T[k * PD + j];
            float a = mem_init[k];
#pragma unroll
            for (int b = 0; b < BSZ; ++b) acc[b] = fmaf(a, w, acc[b]);
        }
    } else {
        const float* mb = memory + (size_t)(s - 1) * MR;
        for (int k = 0; k < MR; ++k) {
            float w = w1T[k * PD + j];
#pragma unroll
            for (int b = 0; b < BSZ; ++b)
                acc[b] = fmaf(mb[(size_t)b * 80000 + k], w, acc[b]);
        }
    }
#pragma unroll
    for (int b = 0; b < BSZ; ++b) h1[b][j] = fmaxf(acc[b], 0.f) * BN;
    __syncthreads();
#pragma unroll
    for (int b = 0; b < BSZ; ++b) acc[b] = 0.f;
    for (int k = 0; k < PD; ++k) {
        float w = w2T[k * PD + j];
#pragma unroll
        for (int b = 0; b < BSZ; ++b) acc[b] = fmaf(h1[b][k], w, acc[b]);
    }
    unsigned short* pH = preH + (size_t)s * BSZ * PD;
    unsigned short* pL = preL + (size_t)s * BSZ * PD;
#pragma unroll
    for (int b = 0; b < BSZ; ++b) {
        float v = fmaxf(acc[b], 0.f) * BN;
        unsigned short h, l; bfsplit(v, h, l);
        pH[b * PD + j] = h; pL[b * PD + j] = l;
    }
}

// ---------------------------------------------------------------------------
// Gate GEMMs via MFMA 16x16x32 bf16, 4-term hi/lo split (fp32-accurate).
// grid 352: [0,224) att = 32 n-tiles(128) x 7 k-chunks(256)
//           [224,352) dec = 16 n-tiles(128) x 8 k-chunks(256)
// B (weights) staged in LDS with (n&7) XOR swizzle; A frags direct global.
// Wave w = m-tile (16 batch rows); 8 n-subtiles of 16 per wave.
// ---------------------------------------------------------------------------
__global__ __launch_bounds__(256) void k_gates(
    int t,
    const unsigned short* __restrict__ preH, const unsigned short* __restrict__ preL,
    const unsigned short* __restrict__ ctxHr, const unsigned short* __restrict__ ctxLr,
    const unsigned short* __restrict__ ctxIH, const unsigned short* __restrict__ ctxIL,
    const unsigned short* __restrict__ qHr, const unsigned short* __restrict__ qLr,
    const unsigned short* __restrict__ qIH, const unsigned short* __restrict__ qIL,
    const unsigned short* __restrict__ dhHr, const unsigned short* __restrict__ dhLr,
    const unsigned short* __restrict__ dhIH, const unsigned short* __restrict__ dhIL,
    const unsigned short* __restrict__ WattH, const unsigned short* __restrict__ WattL,
    const unsigned short* __restrict__ WdecH, const unsigned short* __restrict__ WdecL,
    float* __restrict__ gbufA, float* __restrict__ gbufD) {
    __shared__ unsigned short BsH[128 * 64];
    __shared__ unsigned short BsL[128 * 64];

    int bid = blockIdx.x;
    const unsigned short *aHp, *aLp, *wHp, *wLp;
    float* gout; int NW, K, sA;
    if (bid < 224) {
        if (t >= SSTEP) return;
        int ntile = bid / 7, ks = bid % 7;
        NW = 4096; K = KATT;
        int n0 = ntile * 128;
        wHp = WattH + (size_t)n0 * KATT + ks * 256;
        wLp = WattL + (size_t)n0 * KATT + ks * 256;
        gout = gbufA + (size_t)ks * BSZ * 4096 + n0;
        if (ks == 0) {
            sA = 256; aHp = preH + (size_t)t * BSZ * 256; aLp = preL + (size_t)t * BSZ * 256;
        } else if (ks < 3) {
            sA = 512; int soff = (ks - 1) * 256;
            if (t == 0) { aHp = ctxIH + soff; aLp = ctxIL + soff; }
            else {
                size_t rb = (size_t)((t - 1) & 1) * BSZ * 512;
                aHp = ctxHr + rb + soff; aLp = ctxLr + rb + soff;
            }
        } else {
            sA = 1024; int soff = (ks - 3) * 256;
            if (t == 0) { aHp = qIH + soff; aLp = qIL + soff; }
            else {
                size_t rb = (size_t)((t - 1) & 1) * BSZ * 1024;
                aHp = qHr + rb + soff; aLp = qLr + rb + soff;
            }
        }
    } else {
        if (t < 1) return;
        int r = bid - 224;
        int ntile = r / 8, ks = r % 8;
        NW = 2048; K = KDEC;
        int n0 = ntile * 128;
        wHp = WdecH + (size_t)n0 * KDEC + ks * 256;
        wLp = WdecL + (size_t)n0 * KDEC + ks * 256;
        gout = gbufD + (size_t)ks * BSZ * 2048 + n0;
        if (ks < 4) {
            sA = 1024; int soff = ks * 256;
            size_t rb = (size_t)((t - 1) & 1) * BSZ * 1024;
            aHp = qHr + rb + soff; aLp = qLr + rb + soff;
        } else if (ks < 6) {
            sA = 512; int soff = (ks - 4) * 256;
            size_t rb = (size_t)((t - 1) & 1) * BSZ * 512;
            aHp = ctxHr + rb + soff; aLp = ctxLr + rb + soff;
        } else {
            sA = 512; int soff = (ks - 6) * 256;
            if (t == 1) { aHp = dhIH + soff; aLp = dhIL + soff; }
            else {
                size_t rb = (size_t)((t - 2) & 1) * BSZ * 512;
                aHp = dhHr + rb + soff; aLp = dhLr + rb + soff;
            }
        }
    }

    int tid = threadIdx.x;
    int w = tid >> 6, l = tid & 63;
    int lrow = l & 15, lk = l >> 4;
    const unsigned short* aH0 = aHp + (size_t)(w * 16 + lrow) * sA + lk * 8;
    const unsigned short* aL0 = aLp + (size_t)(w * 16 + lrow) * sA + lk * 8;

    f32x4 acc[8];
#pragma unroll
    for (int ns = 0; ns < 8; ++ns) acc[ns] = (f32x4){0.f, 0.f, 0.f, 0.f};

    for (int ksub = 0; ksub < 4; ++ksub) {
        __syncthreads();
        // stage B hi/lo: 128 n x 64 k, swizzled
#pragma unroll
        for (int r2 = 0; r2 < 4; ++r2) {
            int sl = tid + (r2 << 8);
            int n = sl >> 3, kq = sl & 7;
            size_t goff = (size_t)n * K + ksub * 64 + kq * 8;
            int idx = ((n << 6) | (kq << 3)) ^ ((n & 7) << 3);
            *(uint4*)&BsH[idx] = *(const uint4*)(wHp + goff);
            *(uint4*)&BsL[idx] = *(const uint4*)(wLp + goff);
        }
        __syncthreads();
#pragma unroll
        for (int kk2 = 0; kk2 < 2; ++kk2) {
            bf16x8 aH8 = *(const bf16x8*)(aH0 + ksub * 64 + kk2 * 32);
            bf16x8 aL8 = *(const bf16x8*)(aL0 + ksub * 64 + kk2 * 32);
#pragma unroll
            for (int ns = 0; ns < 8; ++ns) {
                int nl = ns * 16 + lrow;
                int idx = ((nl << 6) | (kk2 * 32 + lk * 8)) ^ ((nl & 7) << 3);
                bf16x8 bH8 = *(const bf16x8*)&BsH[idx];
                bf16x8 bL8 = *(const bf16x8*)&BsL[idx];
                acc[ns] = __builtin_amdgcn_mfma_f32_16x16x32_bf16(aH8, bH8, acc[ns], 0, 0, 0);
                acc[ns] = __builtin_amdgcn_mfma_f32_16x16x32_bf16(aL8, bH8, acc[ns], 0, 0, 0);
                acc[ns] = __builtin_amdgcn_mfma_f32_16x16x32_bf16(aH8, bL8, acc[ns], 0, 0, 0);
                acc[ns] = __builtin_amdgcn_mfma_f32_16x16x32_bf16(aL8, bL8, acc[ns], 0, 0, 0);
            }
        }
    }
    // D frag: row (batch) = w*16 + lk*4 + r, col = ns*16 + lrow
#pragma unroll
    for (int ns = 0; ns < 8; ++ns)
#pragma unroll
        for (int r4 = 0; r4 < 4; ++r4) {
            int b = w * 16 + lk * 4 + r4;
            gout[(size_t)b * NW + ns * 16 + lrow] = acc[ns][r4];
        }
}

// ---------------------------------------------------------------------------
// State kernel: ta_{t-1} -> att pointwise (q_t) -> dec pointwise (dh_{t-1})
//               -> alpha_t (+ alignments) -> ctx_t chunk
// grid: 512 blocks = (b, c8); 256 threads.
// ---------------------------------------------------------------------------
__global__ __launch_bounds__(256) void k_state(
    int t,
    const float* __restrict__ inputs, const float* __restrict__ gbufA,
    const float* __restrict__ gbufD, const float* __restrict__ att_bih,
    const float* __restrict__ att_bhh, const float* __restrict__ dec_bih,
    const float* __restrict__ dec_bhh, const float* __restrict__ ta_u_w,
    const float* __restrict__ ta_u_b, const float* __restrict__ ta_sq_w,
    const float* __restrict__ ta_sq_b, float* ctx_all, float* qbuf,
    float* qc, float* dcbuf, float* dh_all,
    unsigned short* qHr, unsigned short* qLr, unsigned short* ctxHr,
    unsigned short* ctxLr, unsigned short* dhHr, unsigned short* dhLr,
    float* d_out) {
    int bid = blockIdx.x;
    int b = bid >> 3, c8 = bid & 7;
    int tid = threadIdx.x;
    __shared__ float red[256];
    __shared__ float alpha_s[TENC];
    __shared__ float anew[TENC];

    float u = 0.5f, sq = 1.4f;
    // ---- P0: ta for step t-1 ----
    if (t >= 1 && t < SSTEP) {
        const float* ctxp = ctx_all + ((size_t)(t - 1) * BSZ + b) * CTXD;
        const float* qp = qbuf + ((size_t)((t - 1) & 1) * BSZ + b) * QD;
        float du = 0.f, ds = 0.f;
        for (int e = tid; e < CTXD + QD; e += 256) {
            float x = (e < CTXD) ? ctxp[e] : qp[e - CTXD];
            du = fmaf(ta_u_w[e], x, du);
            ds = fmaf(ta_sq_w[e], x, ds);
        }
        red[tid] = du; __syncthreads();
        for (int s2 = 128; s2 > 0; s2 >>= 1) {
            if (tid < s2) red[tid] += red[tid + s2];
            __syncthreads();
        }
        float du_t = red[0]; __syncthreads();
        red[tid] = ds; __syncthreads();
        for (int s2 = 128; s2 > 0; s2 >>= 1) {
            if (tid < s2) red[tid] += red[tid + s2];
            __syncthreads();
        }
        float ds_t = red[0]; __syncthreads();
        u = sigmoidf_(du_t + ta_u_b[0]);
        sq = sigmoidf_(ds_t + ta_sq_b[0]) + 1.f;
    }

    // ---- P1: att-LSTM pointwise, q_t ----
    if (t < SSTEP && tid < 128) {
        int j = c8 * 128 + tid;
        float g4[4];
#pragma unroll
        for (int g = 0; g < 4; ++g) {
            int n = g * QD + j;
            float s = att_bih[n] + att_bhh[n];
            for (int ks = 0; ks < 7; ++ks) s += gbufA[((size_t)ks * BSZ + b) * 4096 + n];
            g4[g] = s;
        }
        float ig = sigmoidf_(g4[0]), fg = sigmoidf_(g4[1]);
        float gg = tanhf(g4[2]), og = sigmoidf_(g4[3]);
        size_t qi = (size_t)b * QD + j;
        float c2 = fg * qc[qi] + ig * gg;
        qc[qi] = c2;
        float hv = og * tanhf(c2);
        qbuf[(size_t)(t & 1) * BSZ * QD + qi] = hv;
        unsigned short hh, ll; bfsplit(hv, hh, ll);
        size_t ri = (size_t)(t & 1) * BSZ * QD + qi;
        qHr[ri] = hh; qLr[ri] = ll;
    }

    // ---- P2: dec-LSTM pointwise, dh_{t-1} ----
    if (t >= 1 && tid < 64) {
        int j = c8 * 64 + tid;
        float g4[4];
#pragma unroll
        for (int g = 0; g < 4; ++g) {
            int n = g * DD + j;
            float s = dec_bih[n] + dec_bhh[n];
            for (int ks = 0; ks < 8; ++ks) s += gbufD[((size_t)ks * BSZ + b) * 2048 + n];
            g4[g] = s;
        }
        float ig = sigmoidf_(g4[0]), fg = sigmoidf_(g4[1]);
        float gg = tanhf(g4[2]), og = sigmoidf_(g4[3]);
        size_t di = (size_t)b * DD + j;
        float c2 = fg * dcbuf[di] + ig * gg;
        dcbuf[di] = c2;
        float hv = og * tanhf(c2);
        dh_all[((size_t)(t - 1) * BSZ + b) * DD + j] = hv;
        unsigned short hh, ll; bfsplit(hv, hh, ll);
        size_t ri = (size_t)((t - 1) & 1) * BSZ * DD + di;
        dhHr[ri] = hh; dhLr[ri] = ll;
    }

    // ---- P3+P4: alpha recursion, normalize, alignments, ctx chunk ----
    if (t < SSTEP) {
        const float* aprev = d_out + ALIGN0 + ((size_t)b * SSTEP + (t - 1)) * TENC;
        for (int e = tid; e < TENC; e += 256)
            alpha_s[e] = (t == 0) ? (e == 0 ? 1.f : 1e-7f) : aprev[e];
        __syncthreads();
        float psum = 0.f;
        for (int e = tid; e < TENC; e += 256) {
            float av = alpha_s[e];
            float sh = (e == 0) ? 0.f : alpha_s[e - 1];
            float a = fmaf(1.f - u, av, u * sh) + 1e-6f;
            a = powf(a, sq);
            anew[e] = a;
            psum += a;
        }
        red[tid] = psum; __syncthreads();
        for (int s2 = 128; s2 > 0; s2 >>= 1) {
            if (tid < s2) red[tid] += red[tid + s2];
            __syncthreads();
        }
        float inv = 1.f / red[0];
        float* aout = d_out + ALIGN0 + ((size_t)b * SSTEP + t) * TENC;
        for (int e = tid; e < TENC; e += 256) {
            float an = anew[e] * inv;
            alpha_s[e] = an;
            if (c8 == 0) aout[e] = an;
        }
        __syncthreads();
        // ctx chunk: d = c8*64 + (tid&63), e-quarters over tid>>6
        int d = c8 * 64 + (tid & 63);
        int q4 = tid >> 6;
        const float* inp = inputs + (size_t)b * TENC * CTXD + d;
        float ps = 0.f;
        int e0 = q4 * 128;
#pragma unroll 8
        for (int e = e0; e < e0 + 128; ++e)
            ps = fmaf(alpha_s[e], inp[(size_t)e * CTXD], ps);
        red[tid] = ps; __syncthreads();
        if (tid < 64) {
            float v = red[tid] + red[tid + 64] + red[tid + 128] + red[tid + 192];
            int dcol = c8 * 64 + tid;
            ctx_all[((size_t)t * BSZ + b) * CTXD + dcol] = v;
            unsigned short hh, ll; bfsplit(v, hh, ll);
            size_t ri = (size_t)(t & 1) * BSZ * CTXD + (size_t)b * CTXD + dcol;
            ctxHr[ri] = hh; ctxLr[ri] = ll;
        }
    }
}

// ---------------------------------------------------------------------------
// Deferred projection (fp32): tmp_out[t][b][j] = [dh_t, ctx_t] @ proj_w.T + b
// ---------------------------------------------------------------------------
__global__ __launch_bounds__(256) void k_proj(
    const float* __restrict__ dh_all, const float* __restrict__ ctx_all,
    const float* __restrict__ projT, const float* __restrict__ proj_b,
    float* __restrict__ tmp_out) {
    int t = blockIdx.x >> 1, bh = blockIdx.x & 1;
    int j = threadIdx.x;
    if (j >= MR) return;
    float acc[32];
#pragma unroll
    for (int i = 0; i < 32; ++i) acc[i] = 0.f;
    int b0 = bh * 32;
    const float* dhp = dh_all + ((size_t)t * BSZ + b0) * DD;
    const float* cxp = ctx_all + ((size_t)t * BSZ + b0) * CTXD;
    for (int k = 0; k < DD; ++k) {
        float w = projT[(size_t)k * MR + j];
#pragma unroll
        for (int i = 0; i < 32; ++i) acc[i] = fmaf(dhp[(size_t)i * DD + k], w, acc[i]);
    }
    for (int k = 0; k < CTXD; ++k) {
        float w = projT[(size_t)(DD + k) * MR + j];
#pragma unroll
        for (int i = 0; i < 32; ++i) acc[i] = fmaf(cxp[(size_t)i * CTXD + k], w, acc[i]);
    }
    float bias = proj_b[j];
    float* o = tmp_out + ((size_t)t * BSZ + b0) * MR + j;
#pragma unroll
    for (int i = 0; i < 32; ++i) o[(size_t)i * MR] = acc[i] + bias;
}

// ---------------------------------------------------------------------------
// Output transpose: d_out[b][m][2t+r] = tmp_out[t][b][r*80+m]
// ---------------------------------------------------------------------------
__global__ __launch_bounds__(256) void k_otrans(const float* __restrict__ tmp_out,
                                                float* __restrict__ d_out) {
    int bid = blockIdx.x;
    int b = bid / 10, tt = bid % 10;
    int t0 = tt * 50;
    __shared__ float tile[50 * MR];
    for (int i = threadIdx.x; i < 50 * MR; i += 256) {
        int trow = i / MR, j = i % MR;
        tile[i] = tmp_out[((size_t)(t0 + trow) * BSZ + b) * MR + j];
    }
    __syncthreads();
    for (int i = threadIdx.x; i < 80 * 100; i += 256) {
        int m = i / 100, ff = i % 100;
        int trow = ff >> 1, r = ff & 1;
        d_out[(size_t)b * 80000 + (size_t)m * 1000 + 2 * t0 + ff] =
            tile[trow * MR + r * 80 + m];
    }
}

// ---------------------------------------------------------------------------
extern "C" void kernel_launch(void* const* d_in, const int* in_sizes, int n_in,
                              void* d_out_v, int out_size, void* d_ws, size_t ws_size,
                              hipStream_t stream) {
    const float* inputs   = (const float*)d_in[0];
    const float* memory   = (const float*)d_in[1];
    const float* w1       = (const float*)d_in[3];
    const float* w2       = (const float*)d_in[4];
    const float* att_wih  = (const float*)d_in[5];
    const float* att_whh  = (const float*)d_in[6];
    const float* att_bih  = (const float*)d_in[7];
    const float* att_bhh  = (const float*)d_in[8];
    const float* ta_u_w   = (const float*)d_in[9];
    const float* ta_u_b   = (const float*)d_in[10];
    const float* ta_sq_w  = (const float*)d_in[11];
    const float* ta_sq_b  = (const float*)d_in[12];
    const float* dec_wih  = (const float*)d_in[13];
    const float* dec_whh  = (const float*)d_in[14];
    const float* dec_bih  = (const float*)d_in[15];
    const float* dec_bhh  = (const float*)d_in[16];
    const float* proj_w   = (const float*)d_in[17];
    const float* proj_b   = (const float*)d_in[18];
    const float* q_init   = (const float*)d_in[19];
    const float* ctx_init = (const float*)d_in[20];
    const float* dh_init  = (const float*)d_in[21];
    const float* mem_init = (const float*)d_in[22];
    float* out = (float*)d_out_v;

    // byte arena with 256-B alignment
    char* base = (char*)d_ws;
    size_t off = 0;
    auto alloc = [&](size_t bytes) -> char* {
        off = (off + 255) & ~(size_t)255;
        char* p = base + off; off += bytes; return p;
    };
    unsigned short* WattH = (unsigned short*)alloc((size_t)4096 * KATT * 2);
    unsigned short* WattL = (unsigned short*)alloc((size_t)4096 * KATT * 2);
    unsigned short* WdecH = (unsigned short*)alloc((size_t)2048 * KDEC * 2);
    unsigned short* WdecL = (unsigned short*)alloc((size_t)2048 * KDEC * 2);
    unsigned short* preH  = (unsigned short*)alloc((size_t)SSTEP * BSZ * PD * 2);
    unsigned short* preL  = (unsigned short*)alloc((size_t)SSTEP * BSZ * PD * 2);
    float* w1T    = (float*)alloc((size_t)160 * 256 * 4);
    float* w2T    = (float*)alloc((size_t)256 * 256 * 4);
    float* projT  = (float*)alloc((size_t)1024 * 160 * 4);
    float* gbufA  = (float*)alloc((size_t)7 * BSZ * 4096 * 4);
    float* gbufD  = (float*)alloc((size_t)8 * BSZ * 2048 * 4);
    float* qbuf   = (float*)alloc((size_t)2 * BSZ * QD * 4);
    float* qc     = (float*)alloc((size_t)BSZ * QD * 4);
    float* dc     = (float*)alloc((size_t)BSZ * DD * 4);
    float* dh_all = (float*)alloc((size_t)SSTEP * BSZ * DD * 4);
    float* ctx_all= (float*)alloc((size_t)SSTEP * BSZ * CTXD * 4);
    float* tmp_out= (float*)alloc((size_t)SSTEP * BSZ * MR * 4);
    unsigned short* qHr   = (unsigned short*)alloc((size_t)2 * BSZ * QD * 2);
    unsigned short* qLr   = (unsigned short*)alloc((size_t)2 * BSZ * QD * 2);
    unsigned short* ctxHr = (unsigned short*)alloc((size_t)2 * BSZ * CTXD * 2);
    unsigned short* ctxLr = (unsigned short*)alloc((size_t)2 * BSZ * CTXD * 2);
    unsigned short* dhHr  = (unsigned short*)alloc((size_t)2 * BSZ * DD * 2);
    unsigned short* dhLr  = (unsigned short*)alloc((size_t)2 * BSZ * DD * 2);
    unsigned short* qIH   = (unsigned short*)alloc((size_t)BSZ * QD * 2);
    unsigned short* qIL   = (unsigned short*)alloc((size_t)BSZ * QD * 2);
    unsigned short* cIH   = (unsigned short*)alloc((size_t)BSZ * CTXD * 2);
    unsigned short* cIL   = (unsigned short*)alloc((size_t)BSZ * CTXD * 2);
    unsigned short* dIH   = (unsigned short*)alloc((size_t)BSZ * DD * 2);
    unsigned short* dIL   = (unsigned short*)alloc((size_t)BSZ * DD * 2);
    (void)ws_size; (void)in_sizes; (void)n_in; (void)out_size;

    dim3 tt(32, 8);
    // small weight transposes (prenet + proj)
    k_transpose<<<dim3(5, 8), tt, 0, stream>>>(w1, w1T, 256, 160, 256, 0);
    k_transpose<<<dim3(8, 8), tt, 0, stream>>>(w2, w2T, 256, 256, 256, 0);
    k_transpose<<<dim3(32, 5), tt, 0, stream>>>(proj_w, projT, 160, 1024, 160, 0);
    // zero LSTM cell states (qc, dc contiguous)
    k_zero<<<dim3(384), dim3(256), 0, stream>>>(qc, BSZ * QD + BSZ * DD);
    // one-time bf16 hi/lo splits
    k_wsplit_att<<<dim3(28672), dim3(256), 0, stream>>>(att_wih, att_whh, WattH, WattL);
    k_wsplit_dec<<<dim3(16384), dim3(256), 0, stream>>>(dec_wih, dec_whh, WdecH, WdecL);
    k_initsplit<<<dim3(512), dim3(256), 0, stream>>>(q_init, ctx_init, dh_init,
                                                     qIH, qIL, cIH, cIL, dIH, dIL);
    // prenet for all steps (writes bf16 hi/lo)
    k_prenet<<<dim3(SSTEP), dim3(256), 0, stream>>>(memory, mem_init, w1T, w2T, preH, preL);

    // main recurrence: 2 kernels per step
    for (int t = 0; t <= SSTEP; ++t) {
        k_gates<<<dim3(352), dim3(256), 0, stream>>>(
            t, preH, preL, ctxHr, ctxLr, cIH, cIL, qHr, qLr, qIH, qIL,
            dhHr, dhLr, dIH, dIL, WattH, WattL, WdecH, WdecL, gbufA, gbufD);
        k_state<<<dim3(512), dim3(256), 0, stream>>>(
            t, inputs, gbufA, gbufD, att_bih, att_bhh, dec_bih, dec_bhh,
            ta_u_w, ta_u_b, ta_sq_w, ta_sq_b, ctx_all, qbuf, qc, dc, dh_all,
            qHr, qLr, ctxHr, ctxLr, dhHr, dhLr, out);
    }

    // deferred projection + output layout transpose
    k_proj<<<dim3(1000), dim3(256), 0, stream>>>(dh_all, ctx_all, projT, proj_b, tmp_out);
    k_otrans<<<dim3(640), dim3(256), 0, stream>>>(tmp_out, out);
}